// Round 11
// baseline (279.429 us; speedup 1.0000x reference)
//
#include <hip/hip_runtime.h>

// ARIMA flow sampling, R11 = R10 (verified, absmax 0.0078125) restructured to
// TWO batches per WG. R10 counters: VALUBusy 55 + MfmaUtil 21.5 = 77%; ~23%
// all-wave barrier drain at exactly-4-WGs/CU residency. Fix: grid 512, each WG
// owns 2 independent batches -> per barrier-phase each wave runs two
// independent GEMM chains (2x ILP between barriers), barriers per batch-step
// halve (1 vs 2). Weight frags shared across the pair (loaded once).
// Clamp via v_med3_f32 (packed f32 min/max doesn't exist; med3 = 1 op).
// Per-element arithmetic IDENTICAL to R10 -> absmax must stay 0.0078125.
//
// Algebra:
//   z_s := W1'[x_s, t_s, 1]  (L1 preact, fp32 in MFMA accumulators)
//   h1 = tanh(z); h2 = tanh(W2'[h1,1])           (GEMM 1)
//   z += dtM @ h2 + v        dtM = dt*W1x@W3     (GEMM 2, acc_in = z)
//   x_100 = W3'[dt*sum_s h2_s, 1]                (x_0 cancels: 100*dt == 1)
// v = sv - dt*z_0 per-row in regs; t folded into v; biases as input feats.

#define NB 1024
#define NQ 96
#define NC 16
#define NH 100
#define QP1 97
#define QP2 98
#define NTHR 256
#define STR 136
#define NSTEPS_ 100
#define MT_K 128  // dtM row stride (bf16)

typedef __attribute__((ext_vector_type(8))) short bf16x8;
typedef __attribute__((ext_vector_type(4))) float f32x4;
typedef __attribute__((ext_vector_type(2))) unsigned uintx2;

__device__ __forceinline__ f32x4 splat4(float f) {
  f32x4 v = f;
  return v;
}

__device__ __forceinline__ short f2bf_rne(float f) {  // one-time paths only
  unsigned u = __builtin_bit_cast(unsigned, f);
  u = u + 0x7fffu + ((u >> 16) & 1u);
  return (short)(u >> 16);
}

// pack two half-up-rounded bf16 into one dword: lo=bf(a), hi=bf(b)
__device__ __forceinline__ unsigned pack_bf2(float a, float b) {
  unsigned ua = __builtin_bit_cast(unsigned, a) + 0x8000u;
  unsigned ub = __builtin_bit_cast(unsigned, b) + 0x8000u;
  return __builtin_amdgcn_perm(ub, ua, 0x07060302);
}

// Pade(5,4) tanh on f32x4; pk-f32 for poly, med3 clamp (== min(max(v,-1),1)
// for all finite v; den>0 so v is finite).
__device__ __forceinline__ f32x4 tanh4(f32x4 x) {
  f32x4 u = x * x;
  f32x4 num =
      x * __builtin_elementwise_fma(u + splat4(105.0f), u, splat4(945.0f));
  f32x4 den = __builtin_elementwise_fma(
      __builtin_elementwise_fma(splat4(15.0f), u, splat4(420.0f)), u,
      splat4(945.0f));
  f32x4 r, v;
  r[0] = __builtin_amdgcn_rcpf(den[0]);
  r[1] = __builtin_amdgcn_rcpf(den[1]);
  r[2] = __builtin_amdgcn_rcpf(den[2]);
  r[3] = __builtin_amdgcn_rcpf(den[3]);
  v = num * r;
  f32x4 o;
  o[0] = __builtin_amdgcn_fmed3f(v[0], -1.0f, 1.0f);
  o[1] = __builtin_amdgcn_fmed3f(v[1], -1.0f, 1.0f);
  o[2] = __builtin_amdgcn_fmed3f(v[2], -1.0f, 1.0f);
  o[3] = __builtin_amdgcn_fmed3f(v[3], -1.0f, 1.0f);
  return o;
}

// ---------------- prep: dtM = dt * W1x @ W3 (bf16) + s-vec ----------------
__global__ void __launch_bounds__(512) arima_prep(
    const float* __restrict__ W1, const float* __restrict__ b1,
    const float* __restrict__ W3, const float* __restrict__ b3,
    short* __restrict__ Mt, float* __restrict__ sv) {
  __shared__ float part[4][128];
  __shared__ float pb[128];
  const int n = blockIdx.x;
  const int tid = threadIdx.x;
  const int k = tid & 127, js = tid >> 7;
  float s = 0.0f;
  if (n < NH && k < NH) {
    int j0 = js * 25, j1 = (js == 3) ? QP1 : j0 + 25;
    for (int j = j0; j < j1; ++j)
      s = fmaf(W1[n * QP2 + j], W3[j * NH + k], s);
  }
  part[js][k] = s;
  if (tid < 128)
    pb[tid] = (tid < QP1 && n < NH) ? W1[n * QP2 + tid] * b3[tid] : 0.0f;
  __syncthreads();
  if (js == 0) {
    float tot = part[0][k] + part[1][k] + part[2][k] + part[3][k];
    Mt[n * MT_K + k] = f2bf_rne(0.01f * tot);
  }
  if (tid == 0) {
    float d = 0.0f;
    for (int j = 0; j < 128; ++j) d += pb[j];
    sv[n] = (n < NH) ? 0.01f * (d + b1[n] + W1[n * QP2 + QP1]) : 0.0f;
  }
}

// ---------------- main ----------------
__device__ void load_afrag(const float* __restrict__ W,
                           const float* __restrict__ bias, int ws, int mvalid,
                           int KW, int m, int quad, bf16x8 dst[4]) {
#pragma unroll
  for (int kb = 0; kb < 4; ++kb) {
    bf16x8 v;
#pragma unroll
    for (int i = 0; i < 8; ++i) {
      int k = kb * 32 + quad * 8 + i;
      float f = 0.0f;
      if (m < mvalid) {
        if (k < KW) f = W[m * ws + k];
        else if (k == KW) f = bias[m];
      }
      v[i] = f2bf_rne(f);
    }
    dst[kb] = v;
  }
}

// acc += A * B(LDS). 2 tiles, K=128. acc carries in (z-update GEMM).
__device__ __forceinline__ void gemm_acc(const short* __restrict__ src,
                                         int rbase, const bf16x8 (&A)[2][4],
                                         f32x4 (&acc)[2]) {
#pragma unroll
  for (int kb = 0; kb < 4; ++kb) {
    bf16x8 bv = *(const bf16x8*)(src + rbase + kb * 32);  // 16B aligned
    acc[0] = __builtin_amdgcn_mfma_f32_16x16x32_bf16(A[0][kb], bv, acc[0], 0, 0, 0);
    acc[1] = __builtin_amdgcn_mfma_f32_16x16x32_bf16(A[1][kb], bv, acc[1], 0, 0, 0);
  }
}

// pack + b64-store both tiles to [row][feat] layout.
__device__ __forceinline__ void write_tiles(short* __restrict__ dst, int wrow,
                                            int T0, int quad, const f32x4& v0,
                                            const f32x4& v1) {
  uintx2 a, b;
  a.x = pack_bf2(v0[0], v0[1]);
  a.y = pack_bf2(v0[2], v0[3]);
  b.x = pack_bf2(v1[0], v1[1]);
  b.y = pack_bf2(v1[2], v1[3]);
  *(uintx2*)(dst + wrow + T0 * 16 + quad * 4) = a;
  *(uintx2*)(dst + wrow + (T0 + 1) * 16 + quad * 4) = b;
}

__global__ void __launch_bounds__(NTHR, 3)
arima_r11(const float* __restrict__ series,
          const float* __restrict__ rand_error, const float* __restrict__ W1,
          const float* __restrict__ b1, const float* __restrict__ W2,
          const float* __restrict__ b2, const float* __restrict__ W3,
          const float* __restrict__ b3, const short* __restrict__ Mt,
          const float* __restrict__ sv, float* __restrict__ out) {
  // [batch-in-pair][h1 | h2] buffers
  __shared__ __align__(16) short bh1[2][16 * STR];  // h1 (feat 100 = 1.0)
  __shared__ __align__(16) short bh2[2][16 * STR];  // x0 / h2 / H2avg

  const int tid = threadIdx.x;
  const int w = tid >> 6, l = tid & 63;
  const int col = l & 15, quad = l >> 4;  // col = channel = data row
  const int b0 = blockIdx.x * 2;          // WG = batches b0, b0+1
  const int T0 = 2 * w;                   // wave owns neuron tiles 2w, 2w+1
  const int wrow = col * STR;
  const int rbase = wrow + quad * 8;
  const bool fixw = (w == 3 && quad == 1);  // owns feat 100 (tile 6, reg 0)

  // ---- x0 -> bh2[p] : feats [x0(97), t0=0, 1, 0...] ----
#pragma unroll
  for (int p = 0; p < 2; ++p) {
    f32x4 xv[2];
#pragma unroll
    for (int t = 0; t < 2; ++t)
#pragma unroll
      for (int r = 0; r < 4; ++r) {
        int q = (T0 + t) * 16 + quad * 4 + r;
        float f = 0.0f;
        if (q < NQ) f = series[((b0 + p) * NQ + q) * NC + col];
        else if (q == NQ) f = rand_error[(b0 + p) * NC + col];
        else if (q == QP2) f = 1.0f;  // bias feature (q==97: t0 = 0)
        xv[t][r] = f;
      }
    write_tiles(bh2[p], wrow, T0, quad, xv[0], xv[1]);
  }
  __syncthreads();

  // ---- z0 = W1'[x0,0,1] ; v = sv - dt*z0 ; h1_0 -> bh1[p] ----
  f32x4 z[2][2], v[2][2];  // [pair][tile]
  {
    bf16x8 a1[2][4];  // transient, shared across the pair
#pragma unroll
    for (int t = 0; t < 2; ++t)
      load_afrag(W1, b1, QP2, NH, QP2, (T0 + t) * 16 + col, quad, a1[t]);
    f32x4 s[2];
#pragma unroll
    for (int t = 0; t < 2; ++t)
#pragma unroll
      for (int r = 0; r < 4; ++r) s[t][r] = sv[(T0 + t) * 16 + quad * 4 + r];
#pragma unroll
    for (int p = 0; p < 2; ++p) {
      z[p][0] = splat4(0.0f);
      z[p][1] = splat4(0.0f);
      gemm_acc(bh2[p], rbase, a1, z[p]);
#pragma unroll
      for (int t = 0; t < 2; ++t) v[p][t] = s[t] - splat4(0.01f) * z[p][t];
      f32x4 h0 = tanh4(z[p][0]), h1 = tanh4(z[p][1]);
      if (fixw) h0[0] = 1.0f;  // h1 feat 100 = 1.0 (W2 bias input)
      write_tiles(bh1[p], wrow, T0, quad, h0, h1);
    }
  }
  __syncthreads();

  // ---- persistent frags: W2' + dtM (shared across the pair) ----
  bf16x8 a2[2][4], am[2][4];
#pragma unroll
  for (int t = 0; t < 2; ++t) {
    load_afrag(W2, b2, NH, NH, NH, (T0 + t) * 16 + col, quad, a2[t]);
#pragma unroll
    for (int kb = 0; kb < 4; ++kb)
      am[t][kb] = *(const bf16x8*)(Mt + ((T0 + t) * 16 + col) * MT_K +
                                   kb * 32 + quad * 8);
  }
  f32x4 h2s[2][2] = {{splat4(0.0f), splat4(0.0f)},
                     {splat4(0.0f), splat4(0.0f)}};

#pragma unroll 1
  for (int step = 0; step < NSTEPS_; ++step) {
    // Phase 1: h2 = tanh(W2'[h1,1]) for BOTH batches, then one barrier.
#pragma unroll
    for (int p = 0; p < 2; ++p) {
      f32x4 acc[2];
      acc[0] = splat4(0.0f);
      acc[1] = splat4(0.0f);
      gemm_acc(bh1[p], rbase, a2, acc);
      f32x4 h0 = tanh4(acc[0]), h1 = tanh4(acc[1]);
      write_tiles(bh2[p], wrow, T0, quad, h0, h1);
      h2s[p][0] = h2s[p][0] + h0;
      h2s[p][1] = h2s[p][1] + h1;
    }
    __syncthreads();
    // Phase 2: z += dtM h2 + v ; h1' = tanh(z) for BOTH batches, one barrier.
#pragma unroll
    for (int p = 0; p < 2; ++p) {
      gemm_acc(bh2[p], rbase, am, z[p]);
      z[p][0] = z[p][0] + v[p][0];
      z[p][1] = z[p][1] + v[p][1];
      f32x4 h0 = tanh4(z[p][0]), h1 = tanh4(z[p][1]);
      if (fixw) h0[0] = 1.0f;
      write_tiles(bh1[p], wrow, T0, quad, h0, h1);
    }
    __syncthreads();
  }

  // ---- out = W3'[dt*H2sum, 1] per batch ----
#pragma unroll
  for (int p = 0; p < 2; ++p) {
    f32x4 ha0 = splat4(0.01f) * h2s[p][0];
    f32x4 ha1 = splat4(0.01f) * h2s[p][1];
    if (fixw) ha0[0] = 1.0f;  // bias feature for b3
    write_tiles(bh2[p], wrow, T0, quad, ha0, ha1);
  }
  __syncthreads();
  {
    bf16x8 a3[2][4];
#pragma unroll
    for (int t = 0; t < 2; ++t)
      load_afrag(W3, b3, NH, QP1, NH, (T0 + t) * 16 + col, quad, a3[t]);
#pragma unroll
    for (int p = 0; p < 2; ++p) {
      f32x4 o[2];
      o[0] = splat4(0.0f);
      o[1] = splat4(0.0f);
      gemm_acc(bh2[p], rbase, a3, o);
#pragma unroll
      for (int t = 0; t < 2; ++t)
#pragma unroll
        for (int r = 0; r < 4; ++r) {
          int q = (T0 + t) * 16 + quad * 4 + r;
          if (q < QP1) out[((b0 + p) * QP1 + q) * NC + col] = o[t][r];
        }
    }
  }
}

extern "C" void kernel_launch(void* const* d_in, const int* in_sizes, int n_in,
                              void* d_out, int out_size, void* d_ws,
                              size_t ws_size, hipStream_t stream) {
  const float* series = (const float*)d_in[0];
  const float* rand_error = (const float*)d_in[1];
  const float* W1 = (const float*)d_in[2];
  const float* b1 = (const float*)d_in[3];
  const float* W2 = (const float*)d_in[4];
  const float* b2 = (const float*)d_in[5];
  const float* W3 = (const float*)d_in[6];
  const float* b3 = (const float*)d_in[7];
  float* out = (float*)d_out;

  short* Mt = (short*)d_ws;                             // 128*128*2 = 32768 B
  float* sv = (float*)((char*)d_ws + MT_K * MT_K * 2);  // 128 f32

  hipLaunchKernelGGL(arima_prep, dim3(128), dim3(512), 0, stream, W1, b1, W3,
                     b3, Mt, sv);
  hipLaunchKernelGGL(arima_r11, dim3(NB / 2), dim3(NTHR), 0, stream, series,
                     rand_error, W1, b1, W2, b2, W3, b3, Mt, sv, out);
}

// Round 13
// 261.968 us; speedup vs baseline: 1.0667x; 1.0667x over previous
//
#include <hip/hip_runtime.h>

// ARIMA flow sampling, R13 = byte-identical restore of R10 (session-best
// VERIFIED: passed, bench 263.38us, main kernel 217us, absmax 0.0078125).
// R11 (pairing inside wave) regressed: serialized inter-barrier path, 8
// waves/CU. R12 (pairing across waves, 512-thr WG) was time-neutral AND
// intermittently diverged under graph replay. Conclusion: the two-barrier
// ping-pong at ~217us is this decomposition's floor; barrier count is not
// the limiter (post-barrier LDS->MFMA->tanh dependency chain is).
//
// Algebra:
//   z_s := W1'[x_s, t_s, 1]  (L1 preact, fp32 in MFMA accumulators)
//   h1 = tanh(z); h2 = tanh(W2'[h1,1])           (GEMM 1)
//   z += dtM @ h2 + v        dtM = dt*W1x@W3     (GEMM 2, acc_in = z)
//   x_100 = W3'[dt*sum_s h2_s, 1]                (x_0 cancels: 100*dt == 1)
// v = sv - dt*z_0 per-row in regs; t folded into v; biases as input feats.

#define NB 1024
#define NQ 96
#define NC 16
#define NH 100
#define QP1 97
#define QP2 98
#define NTHR 256
#define STR 136
#define NSTEPS_ 100
#define MT_K 128  // dtM row stride (bf16)

typedef __attribute__((ext_vector_type(8))) short bf16x8;
typedef __attribute__((ext_vector_type(4))) float f32x4;
typedef __attribute__((ext_vector_type(2))) unsigned uintx2;

__device__ __forceinline__ f32x4 splat4(float f) {
  f32x4 v = f;
  return v;
}

__device__ __forceinline__ short f2bf_rne(float f) {  // one-time paths only
  unsigned u = __builtin_bit_cast(unsigned, f);
  u = u + 0x7fffu + ((u >> 16) & 1u);
  return (short)(u >> 16);
}

// pack two half-up-rounded bf16 into one dword: lo=bf(a), hi=bf(b)
__device__ __forceinline__ unsigned pack_bf2(float a, float b) {
  unsigned ua = __builtin_bit_cast(unsigned, a) + 0x8000u;
  unsigned ub = __builtin_bit_cast(unsigned, b) + 0x8000u;
  return __builtin_amdgcn_perm(ub, ua, 0x07060302);
}

// Pade(5,4) tanh on f32x4 (pk-f32 poly, scalar rcp, min/max clamp).
__device__ __forceinline__ f32x4 tanh4(f32x4 x) {
  f32x4 u = x * x;
  f32x4 num = x * __builtin_elementwise_fma(u + splat4(105.0f), u, splat4(945.0f));
  f32x4 den = __builtin_elementwise_fma(
      __builtin_elementwise_fma(splat4(15.0f), u, splat4(420.0f)), u,
      splat4(945.0f));
  f32x4 r;
  r[0] = __builtin_amdgcn_rcpf(den[0]);
  r[1] = __builtin_amdgcn_rcpf(den[1]);
  r[2] = __builtin_amdgcn_rcpf(den[2]);
  r[3] = __builtin_amdgcn_rcpf(den[3]);
  f32x4 v = num * r;
  return __builtin_elementwise_min(
      __builtin_elementwise_max(v, splat4(-1.0f)), splat4(1.0f));
}

// ---------------- prep: dtM = dt * W1x @ W3 (bf16) + s-vec ----------------
// grid 128 (= n), block 512 (k = tid&127, jslice = tid>>7); LDS reduce.
__global__ void __launch_bounds__(512) arima_prep(
    const float* __restrict__ W1, const float* __restrict__ b1,
    const float* __restrict__ W3, const float* __restrict__ b3,
    short* __restrict__ Mt, float* __restrict__ sv) {
  __shared__ float part[4][128];
  __shared__ float pb[128];
  const int n = blockIdx.x;
  const int tid = threadIdx.x;
  const int k = tid & 127, js = tid >> 7;
  float s = 0.0f;
  if (n < NH && k < NH) {
    int j0 = js * 25, j1 = (js == 3) ? QP1 : j0 + 25;
    for (int j = j0; j < j1; ++j)
      s = fmaf(W1[n * QP2 + j], W3[j * NH + k], s);
  }
  part[js][k] = s;
  if (tid < 128)
    pb[tid] = (tid < QP1 && n < NH) ? W1[n * QP2 + tid] * b3[tid] : 0.0f;
  __syncthreads();
  if (js == 0) {
    float tot = part[0][k] + part[1][k] + part[2][k] + part[3][k];
    Mt[n * MT_K + k] = f2bf_rne(0.01f * tot);
  }
  if (tid == 0) {
    float d = 0.0f;
    for (int j = 0; j < 128; ++j) d += pb[j];
    sv[n] = (n < NH) ? 0.01f * (d + b1[n] + W1[n * QP2 + QP1]) : 0.0f;
  }
}

// ---------------- main ----------------
// Weight A-frag from fp32 W: lane holds W'[m][k], k<KW -> W, k==KW -> bias.
__device__ void load_afrag(const float* __restrict__ W,
                           const float* __restrict__ bias, int ws, int mvalid,
                           int KW, int m, int quad, bf16x8 dst[4]) {
#pragma unroll
  for (int kb = 0; kb < 4; ++kb) {
    bf16x8 v;
#pragma unroll
    for (int i = 0; i < 8; ++i) {
      int k = kb * 32 + quad * 8 + i;
      float f = 0.0f;
      if (m < mvalid) {
        if (k < KW) f = W[m * ws + k];
        else if (k == KW) f = bias[m];
      }
      v[i] = f2bf_rne(f);
    }
    dst[kb] = v;
  }
}

// acc += A * B(LDS). 2 tiles, K=128 (4 kb). acc carries in (z-update!).
__device__ __forceinline__ void gemm_acc(const short* __restrict__ src,
                                         int rbase, const bf16x8 (&A)[2][4],
                                         f32x4 (&acc)[2]) {
#pragma unroll
  for (int kb = 0; kb < 4; ++kb) {
    bf16x8 bv = *(const bf16x8*)(src + rbase + kb * 32);  // 16B aligned
    acc[0] = __builtin_amdgcn_mfma_f32_16x16x32_bf16(A[0][kb], bv, acc[0], 0, 0, 0);
    acc[1] = __builtin_amdgcn_mfma_f32_16x16x32_bf16(A[1][kb], bv, acc[1], 0, 0, 0);
  }
}

// pack + b64-store both tiles to [row][feat] layout.
__device__ __forceinline__ void write_tiles(short* __restrict__ dst, int wrow,
                                            int T0, int quad, const f32x4& v0,
                                            const f32x4& v1) {
  uintx2 a, b;
  a.x = pack_bf2(v0[0], v0[1]);
  a.y = pack_bf2(v0[2], v0[3]);
  b.x = pack_bf2(v1[0], v1[1]);
  b.y = pack_bf2(v1[2], v1[3]);
  *(uintx2*)(dst + wrow + T0 * 16 + quad * 4) = a;
  *(uintx2*)(dst + wrow + (T0 + 1) * 16 + quad * 4) = b;
}

__global__ void __launch_bounds__(NTHR, 4)
arima_r13(const float* __restrict__ series,
          const float* __restrict__ rand_error, const float* __restrict__ W1,
          const float* __restrict__ b1, const float* __restrict__ W2,
          const float* __restrict__ b2, const float* __restrict__ W3,
          const float* __restrict__ b3, const short* __restrict__ Mt,
          const float* __restrict__ sv, float* __restrict__ out) {
  __shared__ __align__(16) short buf1[16 * STR];  // h1 (feat 100 = 1.0)
  __shared__ __align__(16) short buf2[16 * STR];  // x0 / h2 / H2avg

  const int tid = threadIdx.x;
  const int w = tid >> 6, l = tid & 63;
  const int col = l & 15, quad = l >> 4;  // col = channel = data row
  const int b = blockIdx.x;               // WG = one batch
  const int T0 = 2 * w;                   // uniform: wave owns tiles 2w,2w+1
  const int wrow = col * STR;
  const int rbase = wrow + quad * 8;
  const bool fixw = (w == 3 && quad == 1);  // owns feat 100 (tile 6, reg 0)

  // ---- x0 -> buf2 : feats [x0(97), t0=0, 1, 0...] ----
  {
    f32x4 xv[2];
#pragma unroll
    for (int t = 0; t < 2; ++t)
#pragma unroll
      for (int r = 0; r < 4; ++r) {
        int q = (T0 + t) * 16 + quad * 4 + r;
        float f = 0.0f;
        if (q < NQ) f = series[(b * NQ + q) * NC + col];
        else if (q == NQ) f = rand_error[b * NC + col];
        else if (q == QP2) f = 1.0f;  // bias feature (q==97: t0 = 0)
        xv[t][r] = f;
      }
    write_tiles(buf2, wrow, T0, quad, xv[0], xv[1]);
  }
  __syncthreads();

  // ---- z0 = W1'[x0,0,1] ; v = sv - dt*z0 ; h1_0 -> buf1 ----
  f32x4 z[2], v[2];
  {
    bf16x8 a1[2][4];  // transient
#pragma unroll
    for (int t = 0; t < 2; ++t)
      load_afrag(W1, b1, QP2, NH, QP2, (T0 + t) * 16 + col, quad, a1[t]);
    z[0] = splat4(0.0f);
    z[1] = splat4(0.0f);
    gemm_acc(buf2, rbase, a1, z);
#pragma unroll
    for (int t = 0; t < 2; ++t) {
      f32x4 s;
#pragma unroll
      for (int r = 0; r < 4; ++r) s[r] = sv[(T0 + t) * 16 + quad * 4 + r];
      v[t] = s - splat4(0.01f) * z[t];
    }
  }
  {
    f32x4 h0 = tanh4(z[0]), h1 = tanh4(z[1]);
    if (fixw) h0[0] = 1.0f;  // h1 feat 100 = 1.0 (W2 bias input)
    write_tiles(buf1, wrow, T0, quad, h0, h1);
  }
  __syncthreads();

  // ---- persistent frags: W2' + dtM ----
  bf16x8 a2[2][4], am[2][4];
#pragma unroll
  for (int t = 0; t < 2; ++t) {
    load_afrag(W2, b2, NH, NH, NH, (T0 + t) * 16 + col, quad, a2[t]);
#pragma unroll
    for (int kb = 0; kb < 4; ++kb)
      am[t][kb] = *(const bf16x8*)(Mt + ((T0 + t) * 16 + col) * MT_K +
                                   kb * 32 + quad * 8);
  }
  f32x4 h2s[2] = {splat4(0.0f), splat4(0.0f)};

#pragma unroll 1
  for (int step = 0; step < NSTEPS_; ++step) {
    // GEMM 1: h2 = tanh(W2'[h1,1]); store, then accumulate H2sum.
    f32x4 acc[2];
    acc[0] = splat4(0.0f);
    acc[1] = splat4(0.0f);
    gemm_acc(buf1, rbase, a2, acc);
    {
      f32x4 h0 = tanh4(acc[0]), h1 = tanh4(acc[1]);
      write_tiles(buf2, wrow, T0, quad, h0, h1);
      h2s[0] = h2s[0] + h0;
      h2s[1] = h2s[1] + h1;
    }
    __syncthreads();
    // GEMM 2: z += dtM h2 (acc_in = z!), z += v ; h1' = tanh(z) -> buf1
    gemm_acc(buf2, rbase, am, z);
    {
      z[0] = z[0] + v[0];
      z[1] = z[1] + v[1];
      f32x4 h0 = tanh4(z[0]), h1 = tanh4(z[1]);
      if (fixw) h0[0] = 1.0f;
      write_tiles(buf1, wrow, T0, quad, h0, h1);
    }
    __syncthreads();
  }

  // ---- out = W3'[dt*H2sum, 1] ----
  {
    f32x4 ha0 = splat4(0.01f) * h2s[0];
    f32x4 ha1 = splat4(0.01f) * h2s[1];
    if (fixw) ha0[0] = 1.0f;  // bias feature for b3
    write_tiles(buf2, wrow, T0, quad, ha0, ha1);
  }
  __syncthreads();
  {
    bf16x8 a3[2][4];
#pragma unroll
    for (int t = 0; t < 2; ++t)
      load_afrag(W3, b3, NH, QP1, NH, (T0 + t) * 16 + col, quad, a3[t]);
    f32x4 o[2];
    o[0] = splat4(0.0f);
    o[1] = splat4(0.0f);
    gemm_acc(buf2, rbase, a3, o);
#pragma unroll
    for (int t = 0; t < 2; ++t)
#pragma unroll
      for (int r = 0; r < 4; ++r) {
        int q = (T0 + t) * 16 + quad * 4 + r;
        if (q < QP1) out[(b * QP1 + q) * NC + col] = o[t][r];
      }
  }
}

extern "C" void kernel_launch(void* const* d_in, const int* in_sizes, int n_in,
                              void* d_out, int out_size, void* d_ws,
                              size_t ws_size, hipStream_t stream) {
  const float* series = (const float*)d_in[0];
  const float* rand_error = (const float*)d_in[1];
  const float* W1 = (const float*)d_in[2];
  const float* b1 = (const float*)d_in[3];
  const float* W2 = (const float*)d_in[4];
  const float* b2 = (const float*)d_in[5];
  const float* W3 = (const float*)d_in[6];
  const float* b3 = (const float*)d_in[7];
  float* out = (float*)d_out;

  short* Mt = (short*)d_ws;                             // 128*128*2 = 32768 B
  float* sv = (float*)((char*)d_ws + MT_K * MT_K * 2);  // 128 f32

  hipLaunchKernelGGL(arima_prep, dim3(128), dim3(512), 0, stream, W1, b1, W3,
                     b3, Mt, sv);
  hipLaunchKernelGGL(arima_r13, dim3(NB), dim3(NTHR), 0, stream, series,
                     rand_error, W1, b1, W2, b2, W3, b3, Mt, sv, out);
}